// Round 5
// baseline (334.474 us; speedup 1.0000x reference)
//
#include <hip/hip_runtime.h>
#include <math.h>

#define B_ 16
#define N_ 288
#define C_ 32
#define H_ 32
#define BN_ (B_ * N_)       // 4608
#define NT 4                // nodes per wave, kernel 1 (round-2 best)

#define TI6 6
#define NTILES6 (N_ / TI6)  // 48
#define TI4 4
#define NTILES4 (N_ / TI4)  // 72

// ---------------------------------------------------------------------------
// PROBE ROUND. Each kernel repeats its work via an internal rep loop whose
// blockIdx is made opaque with "+s" inline asm (stays in SGPR -> scalar
// address math / s_load codegen preserved; prevents cross-rep CSE/hoisting).
// Output values are identical every rep (idempotent). Purpose: push each
// dispatch above the ~40us harness fills so rocprof top-5 shows OUR counters.
// ---------------------------------------------------------------------------

// K1 = round-2 version (NT=4, one wave/block, 1152 blocks). reps=12.
__global__ __launch_bounds__(64) void gru_proj_kernel(
    const float* __restrict__ inputs, const float* __restrict__ states,
    const float* __restrict__ rzW,    const float* __restrict__ rzb,
    const float* __restrict__ hcW,    const float* __restrict__ hcb,
    const float* __restrict__ c1W,    const float* __restrict__ c1b,
    const float* __restrict__ c2W,    const float* __restrict__ c2b,
    float* __restrict__ out_state,
    float* __restrict__ ps1, float* __restrict__ pr1,
    float* __restrict__ ps2, float* __restrict__ pr2, int reps)
{
    const int lane  = threadIdx.x;
    const int o     = lane & 31;
    const int half  = lane >> 5;

    __shared__ float rs_sh[NT][32];
    __shared__ float a_sh[NT][32];

    for (int rep = 0; rep < reps; ++rep) {
        int bx = blockIdx.x;
        asm volatile("" : "+s"(bx));   // opaque, stays scalar
        const int node0 = bx * NT;

        float acc[NT];
        const float rzbias = rzb[lane];
        #pragma unroll
        for (int t = 0; t < NT; ++t) acc[t] = rzbias;

        #pragma unroll
        for (int k = 0; k < C_; ++k) {
            const float wk = rzW[k * 64 + lane];
            #pragma unroll
            for (int t = 0; t < NT; ++t)
                acc[t] = fmaf(inputs[(node0 + t) * C_ + k], wk, acc[t]);
        }
        #pragma unroll
        for (int k = 0; k < H_; ++k) {
            const float wk = rzW[(C_ + k) * 64 + lane];
            #pragma unroll
            for (int t = 0; t < NT; ++t)
                acc[t] = fmaf(states[(node0 + t) * H_ + k], wk, acc[t]);
        }

        float z[NT], st[NT];
        #pragma unroll
        for (int t = 0; t < NT; ++t) {
            const float rzv = 1.0f / (1.0f + __expf(-acc[t]));
            const float r   = __shfl(rzv, o);
            z[t]  = __shfl(rzv, o + 32);
            st[t] = states[(node0 + t) * H_ + o];
            if (lane < 32) rs_sh[t][o] = r * st[t];
        }
        __syncthreads();

        float acc2[NT];
        #pragma unroll
        for (int t = 0; t < NT; ++t) acc2[t] = 0.0f;

        #pragma unroll
        for (int k = 0; k < C_; ++k) {
            const float wk = hcW[k * H_ + o];
            #pragma unroll
            for (int t = 0; t < NT; ++t)
                acc2[t] = fmaf(inputs[(node0 + t) * C_ + k], wk, acc2[t]);
        }
        #pragma unroll
        for (int q = 0; q < 8; ++q) {
            float4 rq[NT];
            #pragma unroll
            for (int t = 0; t < NT; ++t)
                rq[t] = *(const float4*)&rs_sh[t][q * 4];
            #pragma unroll
            for (int k4 = 0; k4 < 4; ++k4) {
                const float wk = hcW[(C_ + q * 4 + k4) * H_ + o];
                #pragma unroll
                for (int t = 0; t < NT; ++t)
                    acc2[t] = fmaf(((const float*)&rq[t])[k4], wk, acc2[t]);
            }
        }

        const float hcbias = hcb[o];
        #pragma unroll
        for (int t = 0; t < NT; ++t) {
            const float e  = __expf(2.0f * (acc2[t] + hcbias));
            const float hc = 1.0f - 2.0f / (e + 1.0f);
            const float ns = z[t] * st[t] + (1.0f - z[t]) * hc;
            if (lane < 32) out_state[(node0 + t) * H_ + o] = ns;
            const float av = fmaxf(ns, 0.0f);
            if (lane < 32) a_sh[t][o] = av;
        }
        __syncthreads();

        const int rb = half * 32;
        float p1[NT], p2[NT];
        const float b1v = c1b[o], b2v = c2b[o];
        #pragma unroll
        for (int t = 0; t < NT; ++t) {
            p1[t] = half ? 0.0f : b1v;
            p2[t] = half ? 0.0f : b2v;
        }
        #pragma unroll
        for (int q = 0; q < 8; ++q) {
            float4 aq[NT];
            #pragma unroll
            for (int t = 0; t < NT; ++t)
                aq[t] = *(const float4*)&a_sh[t][q * 4];
            #pragma unroll
            for (int k4 = 0; k4 < 4; ++k4) {
                const int h    = q * 4 + k4;
                const float w1 = c1W[(rb + h) * H_ + o];
                const float w2 = c2W[(rb + h) * H_ + o];
                #pragma unroll
                for (int t = 0; t < NT; ++t) {
                    const float av = ((const float*)&aq[t])[k4];
                    p1[t] = fmaf(av, w1, p1[t]);
                    p2[t] = fmaf(av, w2, p2[t]);
                }
            }
        }
        float* d1 = half ? pr1 : ps1;
        float* d2 = half ? pr2 : ps2;
        #pragma unroll
        for (int t = 0; t < NT; ++t) {
            d1[(node0 + t) * H_ + o] = p1[t];
            d2[(node0 + t) * H_ + o] = p2[t];
        }
        __syncthreads();
    }
}

// K2 variant A = round-2 version (TI=6, sender rows via uniform s_loads).
__global__ __launch_bounds__(320) void pair_smem_kernel(
    const float* __restrict__ ps1, const float* __restrict__ pr1,
    const float* __restrict__ ps2, const float* __restrict__ pr2,
    const float* __restrict__ w1g, const float* __restrict__ b1g,
    const float* __restrict__ w2g, const float* __restrict__ b2g,
    float* __restrict__ out, int reps)
{
    const int j = threadIdx.x;
    for (int rep = 0; rep < reps; ++rep) {
        int bx = blockIdx.x;
        asm volatile("" : "+s"(bx));
        const int b  = bx / NTILES6;
        const int i0 = (bx % NTILES6) * TI6;
        if (j < N_) {
            const size_t rowbase = (size_t)(b * N_ + i0) * H_;
            float acc1[TI6];
            float4 p[8];
            float  wv[32];
            {
                const float4* prp = (const float4*)(pr1 + (size_t)(b * N_ + j) * H_);
                #pragma unroll
                for (int c = 0; c < 8; ++c) p[c] = prp[c];
                #pragma unroll
                for (int h = 0; h < 32; ++h) wv[h] = w1g[h];
                const float b1 = b1g[0];
                #pragma unroll
                for (int ii = 0; ii < TI6; ++ii) {
                    const float4* sp = (const float4*)(ps1 + rowbase + (size_t)ii * H_);
                    float aA = b1, aB = 0.0f;
                    #pragma unroll
                    for (int c = 0; c < 8; ++c) {
                        const float4 sv = sp[c];
                        const float t0 = fmaxf(sv.x + p[c].x, 0.0f);
                        const float t1 = fmaxf(sv.y + p[c].y, 0.0f);
                        const float t2 = fmaxf(sv.z + p[c].z, 0.0f);
                        const float t3 = fmaxf(sv.w + p[c].w, 0.0f);
                        aA = fmaf(t0, wv[4 * c + 0], aA);
                        aB = fmaf(t1, wv[4 * c + 1], aB);
                        aA = fmaf(t2, wv[4 * c + 2], aA);
                        aB = fmaf(t3, wv[4 * c + 3], aB);
                    }
                    acc1[ii] = aA + aB;
                }
            }
            {
                const float4* prp = (const float4*)(pr2 + (size_t)(b * N_ + j) * H_);
                #pragma unroll
                for (int c = 0; c < 8; ++c) p[c] = prp[c];
                #pragma unroll
                for (int h = 0; h < 32; ++h) wv[h] = w2g[h];
                const float b2 = b2g[0];
                float* orow = out + (size_t)(b * N_ + i0) * N_ + j;
                #pragma unroll
                for (int ii = 0; ii < TI6; ++ii) {
                    const float4* sp = (const float4*)(ps2 + rowbase + (size_t)ii * H_);
                    float aA = b2, aB = 0.0f;
                    #pragma unroll
                    for (int c = 0; c < 8; ++c) {
                        const float4 sv = sp[c];
                        const float t0 = fmaxf(sv.x + p[c].x, 0.0f);
                        const float t1 = fmaxf(sv.y + p[c].y, 0.0f);
                        const float t2 = fmaxf(sv.z + p[c].z, 0.0f);
                        const float t3 = fmaxf(sv.w + p[c].w, 0.0f);
                        aA = fmaf(t0, wv[4 * c + 0], aA);
                        aB = fmaf(t1, wv[4 * c + 1], aB);
                        aA = fmaf(t2, wv[4 * c + 2], aA);
                        aB = fmaf(t3, wv[4 * c + 3], aB);
                    }
                    const float m   = aA + aB;
                    const float sig = 1.0f / (1.0f + __expf(-m));
                    orow[(size_t)ii * N_] = acc1[ii] * sig;
                }
            }
        }
    }
}

// K2 variant B = round-4 version (TI=4, sender rows staged in LDS).
__global__ __launch_bounds__(320) void pair_lds_kernel(
    const float* __restrict__ ps1, const float* __restrict__ pr1,
    const float* __restrict__ ps2, const float* __restrict__ pr2,
    const float* __restrict__ w1g, const float* __restrict__ b1g,
    const float* __restrict__ w2g, const float* __restrict__ b2g,
    float* __restrict__ out, int reps)
{
    const int tid = threadIdx.x;
    __shared__ __align__(16) float s1[TI4 * 32];
    __shared__ __align__(16) float s2[TI4 * 32];

    for (int rep = 0; rep < reps; ++rep) {
        int bx = blockIdx.x;
        asm volatile("" : "+s"(bx));
        const int b  = bx / NTILES4;
        const int i0 = (bx % NTILES4) * TI4;

        __syncthreads();   // prev rep's LDS reads done before re-stage
        const size_t rowbase = (size_t)(b * N_ + i0) * H_;
        if (tid < TI4 * 32)          s1[tid]           = ps1[rowbase + tid];
        else if (tid < 2 * TI4 * 32) s2[tid - TI4 * 32] = ps2[rowbase + (tid - TI4 * 32)];
        __syncthreads();

        const int j = tid;
        if (j < N_) {
            float acc1[TI4];
            float4 p[8];
            float  wv[32];
            {
                const float4* prp = (const float4*)(pr1 + (size_t)(b * N_ + j) * H_);
                #pragma unroll
                for (int c = 0; c < 8; ++c) p[c] = prp[c];
                #pragma unroll
                for (int h = 0; h < 32; ++h) wv[h] = w1g[h];
                const float b1 = b1g[0];
                #pragma unroll
                for (int ii = 0; ii < TI4; ++ii) {
                    const float4* sp = (const float4*)&s1[ii * 32];
                    float aA = b1, aB = 0.0f;
                    #pragma unroll
                    for (int c = 0; c < 8; ++c) {
                        const float4 sv = sp[c];
                        const float t0 = fmaxf(sv.x + p[c].x, 0.0f);
                        const float t1 = fmaxf(sv.y + p[c].y, 0.0f);
                        const float t2 = fmaxf(sv.z + p[c].z, 0.0f);
                        const float t3 = fmaxf(sv.w + p[c].w, 0.0f);
                        aA = fmaf(t0, wv[4 * c + 0], aA);
                        aB = fmaf(t1, wv[4 * c + 1], aB);
                        aA = fmaf(t2, wv[4 * c + 2], aA);
                        aB = fmaf(t3, wv[4 * c + 3], aB);
                    }
                    acc1[ii] = aA + aB;
                }
            }
            {
                const float4* prp = (const float4*)(pr2 + (size_t)(b * N_ + j) * H_);
                #pragma unroll
                for (int c = 0; c < 8; ++c) p[c] = prp[c];
                #pragma unroll
                for (int h = 0; h < 32; ++h) wv[h] = w2g[h];
                const float b2 = b2g[0];
                float* orow = out + (size_t)(b * N_ + i0) * N_ + j;
                #pragma unroll
                for (int ii = 0; ii < TI4; ++ii) {
                    const float4* sp = (const float4*)&s2[ii * 32];
                    float aA = b2, aB = 0.0f;
                    #pragma unroll
                    for (int c = 0; c < 8; ++c) {
                        const float4 sv = sp[c];
                        const float t0 = fmaxf(sv.x + p[c].x, 0.0f);
                        const float t1 = fmaxf(sv.y + p[c].y, 0.0f);
                        const float t2 = fmaxf(sv.z + p[c].z, 0.0f);
                        const float t3 = fmaxf(sv.w + p[c].w, 0.0f);
                        aA = fmaf(t0, wv[4 * c + 0], aA);
                        aB = fmaf(t1, wv[4 * c + 1], aB);
                        aA = fmaf(t2, wv[4 * c + 2], aA);
                        aB = fmaf(t3, wv[4 * c + 3], aB);
                    }
                    const float m   = aA + aB;
                    const float sig = 1.0f / (1.0f + __expf(-m));
                    orow[(size_t)ii * N_] = acc1[ii] * sig;
                }
            }
        }
    }
}

extern "C" void kernel_launch(void* const* d_in, const int* in_sizes, int n_in,
                              void* d_out, int out_size, void* d_ws, size_t ws_size,
                              hipStream_t stream) {
    const float* inputs = (const float*)d_in[0];
    const float* states = (const float*)d_in[1];
    const float* rzW    = (const float*)d_in[2];
    const float* rzb    = (const float*)d_in[3];
    const float* hcW    = (const float*)d_in[4];
    const float* hcb    = (const float*)d_in[5];
    const float* c1W    = (const float*)d_in[6];
    const float* c1b    = (const float*)d_in[7];
    const float* c1w1   = (const float*)d_in[8];
    const float* c1b1   = (const float*)d_in[9];
    const float* c2W    = (const float*)d_in[10];
    const float* c2b    = (const float*)d_in[11];
    const float* c2w1   = (const float*)d_in[12];
    const float* c2b1   = (const float*)d_in[13];

    float* out_support = (float*)d_out;
    float* out_state   = out_support + (size_t)BN_ * N_;

    float* ws  = (float*)d_ws;
    float* ps1 = ws;
    float* pr1 = ws + 1 * (size_t)BN_ * H_;
    float* ps2 = ws + 2 * (size_t)BN_ * H_;
    float* pr2 = ws + 3 * (size_t)BN_ * H_;

    // Probe: surface all three kernels above the ~40us harness fills.
    gru_proj_kernel<<<BN_ / NT, 64, 0, stream>>>(
        inputs, states, rzW, rzb, hcW, hcb, c1W, c1b, c2W, c2b,
        out_state, ps1, pr1, ps2, pr2, 12);

    pair_smem_kernel<<<B_ * NTILES6, 320, 0, stream>>>(
        ps1, pr1, ps2, pr2, c1w1, c1b1, c2w1, c2b1, out_support, 8);

    pair_lds_kernel<<<B_ * NTILES4, 320, 0, stream>>>(
        ps1, pr1, ps2, pr2, c1w1, c1b1, c2w1, c2b1, out_support, 8);
}

// Round 6
// 29.363 us; speedup vs baseline: 11.3911x; 11.3911x over previous
//
#include <hip/hip_runtime.h>
#include <math.h>

#define B_ 16
#define N_ 288
#define C_ 32
#define H_ 32
#define BN_ (B_ * N_)       // 4608

#define K1_NT 2             // nodes per wave
#define K1_NODES 8          // nodes per block (4 waves)

#define TI 4                // i-rows per block in kernel 2
#define NTILES (N_ / TI)    // 72

typedef float v2f __attribute__((ext_vector_type(2)));

// ---------------------------------------------------------------------------
// Kernel 1: GRU cell + projections. 576 blocks x 256 threads (4 waves, 2
// nodes/wave -> 2304 waves, ~12 resident waves/CU). ALL weights staged in LDS
// (40KB, natural [k][unit] layout: weight reads are consecutive-lane
// conflict-free; x reads are b128 broadcasts). Kills the L2-latency dependent
// chain that had VALUBusy at 15%.
// ---------------------------------------------------------------------------
__global__ __launch_bounds__(256) void gru_proj_kernel(
    const float* __restrict__ inputs, const float* __restrict__ states,
    const float* __restrict__ rzW,    const float* __restrict__ rzb,
    const float* __restrict__ hcW,    const float* __restrict__ hcb,
    const float* __restrict__ c1W,    const float* __restrict__ c1b,
    const float* __restrict__ c2W,    const float* __restrict__ c2b,
    float* __restrict__ out_state,
    float* __restrict__ ps1, float* __restrict__ pr1,
    float* __restrict__ ps2, float* __restrict__ pr2)
{
    __shared__ __align__(16) float w_rz[64 * 64];        // [k][64]   16KB
    __shared__ __align__(16) float w_hc[64 * 32];        // [k][32]    8KB
    __shared__ __align__(16) float w_c1[64 * 32];        // [row][32]  8KB
    __shared__ __align__(16) float w_c2[64 * 32];        //            8KB
    __shared__ __align__(16) float x_in[K1_NODES * 32];  // 1KB
    __shared__ __align__(16) float x_st[K1_NODES * 32];  // 1KB
    __shared__ __align__(16) float rs_a[4][K1_NT][32];   // r*s, then a; 1KB

    const int tid = threadIdx.x;

    // ---- stage weights + node data (one barrier) ----
    {
        const float4* s4 = (const float4*)rzW;           // 16B-aligned (4096 f)
        float4* d4 = (float4*)w_rz;
        #pragma unroll
        for (int i = 0; i < 4; ++i) d4[tid + i * 256] = s4[tid + i * 256];
        const float4* sh = (const float4*)hcW;           // 2048 floats
        float4* dh = (float4*)w_hc;
        #pragma unroll
        for (int i = 0; i < 2; ++i) dh[tid + i * 256] = sh[tid + i * 256];
        const float4* sc = (const float4*)c1W;           // 2048 floats
        float4* dc = (float4*)w_c1;
        #pragma unroll
        for (int i = 0; i < 2; ++i) dc[tid + i * 256] = sc[tid + i * 256];
        #pragma unroll
        for (int i = 0; i < 8; ++i)                      // c2W: scalar (4B-align safe)
            w_c2[tid + i * 256] = c2W[tid + i * 256];
        const int nb = blockIdx.x * K1_NODES * 32;       // 256 floats each
        x_in[tid] = inputs[nb + tid];
        x_st[tid] = states[nb + tid];
    }
    __syncthreads();

    const int w     = tid >> 6;
    const int lane  = tid & 63;
    const int o     = lane & 31;
    const int half  = lane >> 5;
    const int ln0   = w * K1_NT;                   // local node of t=0
    const int node0 = blockIdx.x * K1_NODES + ln0;

    // ---- r_z = sigmoid(x @ rzW + rzb); lane = out unit (64) ----
    float acc[K1_NT];
    const float rzbias = rzb[lane];
    acc[0] = rzbias; acc[1] = rzbias;

    #pragma unroll
    for (int q = 0; q < 8; ++q) {                  // k = 0..31 (inputs)
        const float4 xa = *(const float4*)&x_in[(ln0 + 0) * 32 + q * 4];
        const float4 xb = *(const float4*)&x_in[(ln0 + 1) * 32 + q * 4];
        #pragma unroll
        for (int k4 = 0; k4 < 4; ++k4) {
            const float wk = w_rz[(q * 4 + k4) * 64 + lane];
            acc[0] = fmaf(((const float*)&xa)[k4], wk, acc[0]);
            acc[1] = fmaf(((const float*)&xb)[k4], wk, acc[1]);
        }
    }
    #pragma unroll
    for (int q = 0; q < 8; ++q) {                  // k = 32..63 (states)
        const float4 xa = *(const float4*)&x_st[(ln0 + 0) * 32 + q * 4];
        const float4 xb = *(const float4*)&x_st[(ln0 + 1) * 32 + q * 4];
        #pragma unroll
        for (int k4 = 0; k4 < 4; ++k4) {
            const float wk = w_rz[(32 + q * 4 + k4) * 64 + lane];
            acc[0] = fmaf(((const float*)&xa)[k4], wk, acc[0]);
            acc[1] = fmaf(((const float*)&xb)[k4], wk, acc[1]);
        }
    }

    float z[K1_NT], st[K1_NT];
    #pragma unroll
    for (int t = 0; t < K1_NT; ++t) {
        const float rzv = 1.0f / (1.0f + __expf(-acc[t]));
        const float r   = __shfl(rzv, o);
        z[t]  = __shfl(rzv, o + 32);
        st[t] = x_st[(ln0 + t) * 32 + o];
        if (lane < 32) rs_a[w][t][o] = r * st[t];  // wave-private, no barrier
    }

    // ---- h_cand: split-K (half0: k=0..31 from x_in, half1: k=32..63 = r*s) ----
    const float* xs0 = half ? &rs_a[w][0][0] : &x_in[(ln0 + 0) * 32];
    const float* xs1 = half ? &rs_a[w][1][0] : &x_in[(ln0 + 1) * 32];
    float acc2[K1_NT] = {0.0f, 0.0f};
    #pragma unroll
    for (int q = 0; q < 8; ++q) {
        const float4 xa = *(const float4*)&xs0[q * 4];
        const float4 xb = *(const float4*)&xs1[q * 4];
        #pragma unroll
        for (int k4 = 0; k4 < 4; ++k4) {
            const float wk = w_hc[(half * 32 + q * 4 + k4) * 32 + o];
            acc2[0] = fmaf(((const float*)&xa)[k4], wk, acc2[0]);
            acc2[1] = fmaf(((const float*)&xb)[k4], wk, acc2[1]);
        }
    }

    const float hcbias = hcb[o];
    #pragma unroll
    for (int t = 0; t < K1_NT; ++t) {
        acc2[t] += __shfl_xor(acc2[t], 32);
        // tanh(x) = 1 - 2/(exp(2x)+1)
        const float e  = __expf(2.0f * (acc2[t] + hcbias));
        const float hc = 1.0f - 2.0f / (e + 1.0f);
        const float ns = z[t] * st[t] + (1.0f - z[t]) * hc;
        if (lane < 32) out_state[(node0 + t) * H_ + o] = ns;
        if (lane < 32) rs_a[w][t][o] = fmaxf(ns, 0.0f);  // reuse as 'a'
    }

    // ---- projections: lane = [sender unit | receiver unit] ----
    float p1[K1_NT], p2[K1_NT];
    const float b1v = c1b[o], b2v = c2b[o];
    p1[0] = half ? 0.0f : b1v;  p1[1] = p1[0];
    p2[0] = half ? 0.0f : b2v;  p2[1] = p2[0];
    #pragma unroll
    for (int q = 0; q < 8; ++q) {
        const float4 aa = *(const float4*)&rs_a[w][0][q * 4];
        const float4 ab = *(const float4*)&rs_a[w][1][q * 4];
        #pragma unroll
        for (int k4 = 0; k4 < 4; ++k4) {
            const int row  = half * 32 + q * 4 + k4;
            const float w1 = w_c1[row * 32 + o];
            const float w2 = w_c2[row * 32 + o];
            const float a0 = ((const float*)&aa)[k4];
            const float a1 = ((const float*)&ab)[k4];
            p1[0] = fmaf(a0, w1, p1[0]);
            p1[1] = fmaf(a1, w1, p1[1]);
            p2[0] = fmaf(a0, w2, p2[0]);
            p2[1] = fmaf(a1, w2, p2[1]);
        }
    }
    float* d1 = half ? pr1 : ps1;
    float* d2 = half ? pr2 : ps2;
    #pragma unroll
    for (int t = 0; t < K1_NT; ++t) {
        d1[(node0 + t) * H_ + o] = p1[t];
        d2[(node0 + t) * H_ + o] = p2[t];
    }
}

// ---------------------------------------------------------------------------
// Kernel 2: pair conv, LDS-staged sender rows (round-4 winner) + packed-f32
// inner loop (v_pk_add/max/fma via v2f) to halve VALU issue count.
// ---------------------------------------------------------------------------
__global__ __launch_bounds__(320) void pair_kernel(
    const float* __restrict__ ps1, const float* __restrict__ pr1,
    const float* __restrict__ ps2, const float* __restrict__ pr2,
    const float* __restrict__ w1g, const float* __restrict__ b1g,
    const float* __restrict__ w2g, const float* __restrict__ b2g,
    float* __restrict__ out)
{
    const int tid = threadIdx.x;
    const int b   = blockIdx.x / NTILES;
    const int i0  = (blockIdx.x % NTILES) * TI;

    __shared__ __align__(16) float s1[TI * 32];
    __shared__ __align__(16) float s2[TI * 32];

    const size_t rowbase = (size_t)(b * N_ + i0) * H_;
    if (tid < TI * 32)            s1[tid]            = ps1[rowbase + tid];
    else if (tid < 2 * TI * 32)   s2[tid - TI * 32]  = ps2[rowbase + (tid - TI * 32)];
    __syncthreads();

    const int j = tid;
    if (j < N_) {
        const v2f zero = {0.0f, 0.0f};
        float acc1[TI];

        // ---- conv1 (support) ----
        {
            const float4* prp = (const float4*)(pr1 + (size_t)(b * N_ + j) * H_);
            v2f p0[8], p1v[8], w0[8], w1v[8];
            #pragma unroll
            for (int c = 0; c < 8; ++c) {
                const float4 pv = prp[c];
                p0[c]  = (v2f){pv.x, pv.y};
                p1v[c] = (v2f){pv.z, pv.w};
                w0[c]  = (v2f){w1g[4 * c + 0], w1g[4 * c + 1]};
                w1v[c] = (v2f){w1g[4 * c + 2], w1g[4 * c + 3]};
            }
            const float b1 = b1g[0];
            #pragma unroll
            for (int ii = 0; ii < TI; ++ii) {
                v2f aA = {b1, 0.0f}, aB = zero;
                #pragma unroll
                for (int c = 0; c < 8; ++c) {
                    const float4 sv = *(const float4*)&s1[ii * 32 + c * 4];
                    v2f u0 = (v2f){sv.x, sv.y} + p0[c];
                    v2f u1 = (v2f){sv.z, sv.w} + p1v[c];
                    u0 = __builtin_elementwise_max(u0, zero);
                    u1 = __builtin_elementwise_max(u1, zero);
                    aA = u0 * w0[c] + aA;     // contracts to v_pk_fma_f32
                    aB = u1 * w1v[c] + aB;
                }
                acc1[ii] = aA.x + aA.y + aB.x + aB.y;
            }
        }

        // ---- conv2 (mask) + epilogue ----
        {
            const float4* prp = (const float4*)(pr2 + (size_t)(b * N_ + j) * H_);
            v2f p0[8], p1v[8], w0[8], w1v[8];
            #pragma unroll
            for (int c = 0; c < 8; ++c) {
                const float4 pv = prp[c];
                p0[c]  = (v2f){pv.x, pv.y};
                p1v[c] = (v2f){pv.z, pv.w};
                w0[c]  = (v2f){w2g[4 * c + 0], w2g[4 * c + 1]};
                w1v[c] = (v2f){w2g[4 * c + 2], w2g[4 * c + 3]};
            }
            const float b2 = b2g[0];
            float* orow = out + (size_t)(b * N_ + i0) * N_ + j;
            #pragma unroll
            for (int ii = 0; ii < TI; ++ii) {
                v2f aA = {b2, 0.0f}, aB = zero;
                #pragma unroll
                for (int c = 0; c < 8; ++c) {
                    const float4 sv = *(const float4*)&s2[ii * 32 + c * 4];
                    v2f u0 = (v2f){sv.x, sv.y} + p0[c];
                    v2f u1 = (v2f){sv.z, sv.w} + p1v[c];
                    u0 = __builtin_elementwise_max(u0, zero);
                    u1 = __builtin_elementwise_max(u1, zero);
                    aA = u0 * w0[c] + aA;
                    aB = u1 * w1v[c] + aB;
                }
                const float m   = aA.x + aA.y + aB.x + aB.y;
                const float sig = 1.0f / (1.0f + __expf(-m));
                orow[(size_t)ii * N_] = acc1[ii] * sig;
            }
        }
    }
}

extern "C" void kernel_launch(void* const* d_in, const int* in_sizes, int n_in,
                              void* d_out, int out_size, void* d_ws, size_t ws_size,
                              hipStream_t stream) {
    const float* inputs = (const float*)d_in[0];
    const float* states = (const float*)d_in[1];
    const float* rzW    = (const float*)d_in[2];
    const float* rzb    = (const float*)d_in[3];
    const float* hcW    = (const float*)d_in[4];
    const float* hcb    = (const float*)d_in[5];
    const float* c1W    = (const float*)d_in[6];
    const float* c1b    = (const float*)d_in[7];
    const float* c1w1   = (const float*)d_in[8];
    const float* c1b1   = (const float*)d_in[9];
    const float* c2W    = (const float*)d_in[10];
    const float* c2b    = (const float*)d_in[11];
    const float* c2w1   = (const float*)d_in[12];
    const float* c2b1   = (const float*)d_in[13];

    float* out_support = (float*)d_out;
    float* out_state   = out_support + (size_t)BN_ * N_;

    float* ws  = (float*)d_ws;
    float* ps1 = ws;
    float* pr1 = ws + 1 * (size_t)BN_ * H_;
    float* ps2 = ws + 2 * (size_t)BN_ * H_;
    float* pr2 = ws + 3 * (size_t)BN_ * H_;

    gru_proj_kernel<<<BN_ / K1_NODES, 256, 0, stream>>>(
        inputs, states, rzW, rzb, hcW, hcb, c1W, c1b, c2W, c2b,
        out_state, ps1, pr1, ps2, pr2);

    pair_kernel<<<B_ * NTILES, 320, 0, stream>>>(
        ps1, pr1, ps2, pr2, c1w1, c1b1, c2w1, c2b1, out_support);
}